// Round 1
// baseline (562.527 us; speedup 1.0000x reference)
//
#include <hip/hip_runtime.h>
#include <hip/hip_bf16.h>
#include <math.h>

// Problem constants
constexpr int N    = 8192;
constexpr int DIM  = 1024;
constexpr int DKQ  = 64;
constexpr int DV   = 64;

// ---------------------------------------------------------------------------
// Projection: q = x@wq, k = x@wk, v = x@wv   (x:[N,1024], w:[1024,64])
// Block: 16 rows of x, 192 threads (one per output column across q|k|v).
// x tile staged in LDS (all threads broadcast-read the same element).
// w streamed from L2 (3*256KB, fully L2 resident, reused by all 512 blocks).
// ---------------------------------------------------------------------------
__global__ __launch_bounds__(192) void proj_kernel(
    const float* __restrict__ x,
    const float* __restrict__ wq,
    const float* __restrict__ wk,
    const float* __restrict__ wv,
    float* __restrict__ q,
    float* __restrict__ k,
    float* __restrict__ v)
{
    __shared__ float xs[16][64];

    const int tid = threadIdx.x;          // 0..191
    const int cc  = tid & 63;             // column within its matrix
    const float* w   = (tid < 64) ? wq : (tid < 128) ? wk : wv;
    float*       dst = (tid < 64) ? q  : (tid < 128) ? k  : v;

    const int row0 = blockIdx.x * 16;

    float acc[16];
#pragma unroll
    for (int r = 0; r < 16; ++r) acc[r] = 0.f;

    for (int kc = 0; kc < DIM / 64; ++kc) {
        __syncthreads();                          // protect xs from previous pass
        for (int idx = tid; idx < 16 * 64; idx += 192) {
            int rr = idx >> 6, dd = idx & 63;
            xs[rr][dd] = x[(row0 + rr) * DIM + kc * 64 + dd];
        }
        __syncthreads();

#pragma unroll 4
        for (int d = 0; d < 64; ++d) {
            float wval = w[(kc * 64 + d) * 64 + cc];
#pragma unroll
            for (int r = 0; r < 16; ++r)
                acc[r] += xs[r][d] * wval;
        }
    }

#pragma unroll
    for (int r = 0; r < 16; ++r)
        dst[(row0 + r) * 64 + cc] = acc[r];
}

// ---------------------------------------------------------------------------
// Flash attention: out = softmax(q k^T / 8) v
// Block: BQ=16 q-rows, 256 threads. tid = r*16 + p :
//   r = q-row within tile (0..15), p = group (0..15) owning v-dims [4p,4p+4)
// and computing scores j = s*16+p (s=0..3) per k/v tile of BK=64 rows.
// Row groups (16 lanes) are contiguous inside one wave -> shfl reductions,
// and the p-tile (LDS) needs no barrier between write and read.
// ---------------------------------------------------------------------------
constexpr int BQ = 16;
constexpr int BK = 64;

__global__ __launch_bounds__(256) void attn_kernel(
    const float* __restrict__ q,
    const float* __restrict__ k,
    const float* __restrict__ v,
    float* __restrict__ out)
{
    __shared__ float qs[BQ][68];   // pad 68 to spread banks for b128 reads
    __shared__ float ks[BK][68];
    __shared__ float vs[BK][64];
    __shared__ float ps[BQ][68];

    const int tid = threadIdx.x;
    const int r   = tid >> 4;     // q-row within tile
    const int p   = tid & 15;     // column group
    const int qrow0 = blockIdx.x * BQ;

    // load q tile: 16x64 floats = 256 float4, one per thread
    {
        int row = tid >> 4, c4 = tid & 15;
        float4 t = reinterpret_cast<const float4*>(q + (qrow0 + row) * DKQ)[c4];
        *reinterpret_cast<float4*>(&qs[row][c4 * 4]) = t;
    }

    float m = -INFINITY;
    float l = 0.f;
    float4 o = {0.f, 0.f, 0.f, 0.f};

    for (int tile = 0; tile < N / BK; ++tile) {
        __syncthreads();   // ks/vs consumed by all waves (also covers q store, tile 0)
        const float* kg = k + (size_t)tile * BK * DKQ;
        const float* vg = v + (size_t)tile * BK * DV;
#pragma unroll
        for (int i = 0; i < 4; ++i) {
            int idx = tid + i * 256;
            int row = idx >> 4, c4 = idx & 15;
            float4 tk = reinterpret_cast<const float4*>(kg + row * DKQ)[c4];
            *reinterpret_cast<float4*>(&ks[row][c4 * 4]) = tk;
            float4 tv = reinterpret_cast<const float4*>(vg + row * DV)[c4];
            *reinterpret_cast<float4*>(&vs[row][c4 * 4]) = tv;
        }
        __syncthreads();

        // scores for j = s*16 + p  (strided so LDS k-reads spread banks)
        float sc[4];
#pragma unroll
        for (int s = 0; s < 4; ++s) {
            int j = s * 16 + p;
            float ax = 0.f, ay = 0.f, az = 0.f, aw = 0.f;
#pragma unroll
            for (int d4 = 0; d4 < 16; ++d4) {
                float4 qv = *reinterpret_cast<const float4*>(&qs[r][d4 * 4]);
                float4 kv = *reinterpret_cast<const float4*>(&ks[j][d4 * 4]);
                ax += qv.x * kv.x; ay += qv.y * kv.y;
                az += qv.z * kv.z; aw += qv.w * kv.w;
            }
            sc[s] = (ax + ay + az + aw) * 0.125f;
        }

        // online softmax: row-max / row-sum across the 16-lane group
        float tmax = fmaxf(fmaxf(sc[0], sc[1]), fmaxf(sc[2], sc[3]));
#pragma unroll
        for (int w = 1; w < 16; w <<= 1)
            tmax = fmaxf(tmax, __shfl_xor(tmax, w, 64));

        float mnew = fmaxf(m, tmax);
        float corr = __expf(m - mnew);     // exp(-inf)=0 on first tile

        float psum = 0.f;
#pragma unroll
        for (int s = 0; s < 4; ++s) {
            float e = __expf(sc[s] - mnew);
            psum += e;
            ps[r][s * 16 + p] = e;         // same-wave producer/consumer: no barrier
        }
#pragma unroll
        for (int w = 1; w < 16; w <<= 1)
            psum += __shfl_xor(psum, w, 64);

        l = l * corr + psum;
        m = mnew;
        o.x *= corr; o.y *= corr; o.z *= corr; o.w *= corr;

        // PV: o[d] += sum_j p_j * v[j][d], d in [4p, 4p+4)
#pragma unroll 8
        for (int j = 0; j < BK; ++j) {
            float pj = ps[r][j];                                   // broadcast
            float4 vv = *reinterpret_cast<const float4*>(&vs[j][p * 4]);
            o.x += pj * vv.x; o.y += pj * vv.y;
            o.z += pj * vv.z; o.w += pj * vv.w;
        }
    }

    float inv = 1.0f / l;
    float4 res = {o.x * inv, o.y * inv, o.z * inv, o.w * inv};
    reinterpret_cast<float4*>(out + (size_t)(qrow0 + r) * DV)[p] = res;
}

// ---------------------------------------------------------------------------
extern "C" void kernel_launch(void* const* d_in, const int* in_sizes, int n_in,
                              void* d_out, int out_size, void* d_ws, size_t ws_size,
                              hipStream_t stream)
{
    const float* x  = (const float*)d_in[0];
    const float* wq = (const float*)d_in[1];
    const float* wk = (const float*)d_in[2];
    const float* wv = (const float*)d_in[3];
    float* out = (float*)d_out;

    float* q = (float*)d_ws;                       // N*64 floats = 2 MB
    float* k = q + (size_t)N * DKQ;                // 2 MB
    float* v = k + (size_t)N * DKQ;                // 2 MB

    proj_kernel<<<N / 16, 192, 0, stream>>>(x, wq, wk, wv, q, k, v);
    attn_kernel<<<N / BQ, 256, 0, stream>>>(q, k, v, out);
}

// Round 4
// 424.327 us; speedup vs baseline: 1.3257x; 1.3257x over previous
//
#include <hip/hip_runtime.h>
#include <hip/hip_bf16.h>
#include <math.h>

// Problem constants
constexpr int N    = 8192;
constexpr int DIM  = 1024;
constexpr int DKQ  = 64;
constexpr int DV   = 64;

// ---------------------------------------------------------------------------
// Projection: q|k|v = x @ w{q,k,v}.  Block = 16 x-rows, 192 threads.
// Wave g (0..2) owns matrix g; both x-tile and w-chunk staged in LDS so the
// inner loop is LDS-broadcast + FMA only (no L2 latency on critical path).
// ---------------------------------------------------------------------------
__global__ __launch_bounds__(192) void proj_kernel(
    const float* __restrict__ x,
    const float* __restrict__ wq,
    const float* __restrict__ wk,
    const float* __restrict__ wv,
    float* __restrict__ q,
    float* __restrict__ k,
    float* __restrict__ v)
{
    __shared__ float xs[16][64];
    __shared__ float wls[3][64][64];

    const int tid = threadIdx.x;       // 0..191
    const int g   = tid >> 6;          // wave id = matrix id
    const int cc  = tid & 63;
    float* dst = (g == 0) ? q : (g == 1) ? k : v;

    const int row0 = blockIdx.x * 16;

    float acc[16];
#pragma unroll
    for (int r = 0; r < 16; ++r) acc[r] = 0.f;

    for (int kc = 0; kc < DIM / 64; ++kc) {
        __syncthreads();
        // stage x tile (16x64)
#pragma unroll
        for (int it = 0; it < 6; ++it) {
            int idx = tid + it * 192;
            if (idx < 1024)
                xs[idx >> 6][idx & 63] =
                    x[(size_t)(row0 + (idx >> 6)) * DIM + kc * 64 + (idx & 63)];
        }
        // stage w chunks: 3 x 64x64 floats = 3072 float4, 16 per thread
#pragma unroll
        for (int it = 0; it < 16; ++it) {
            int f4  = tid + it * 192;      // 0..3071
            int mg  = f4 >> 10;
            int off = f4 & 1023;
            const float* wsrc = (mg == 0) ? wq : (mg == 1) ? wk : wv;
            *reinterpret_cast<float4*>(&wls[mg][0][0] + off * 4) =
                *reinterpret_cast<const float4*>(wsrc + (size_t)kc * 4096 + off * 4);
        }
        __syncthreads();

#pragma unroll 8
        for (int d = 0; d < 64; ++d) {
            float wval = wls[g][d][cc];     // 64 consecutive words: 2-way, free
#pragma unroll
            for (int r = 0; r < 16; ++r)
                acc[r] += xs[r][d] * wval;  // broadcast read
        }
    }

#pragma unroll
    for (int r = 0; r < 16; ++r)
        dst[(size_t)(row0 + r) * 64 + cc] = acc[r];
}

// ---------------------------------------------------------------------------
// Flash attention, register-tiled, split-K.
// Block: BQ=64 q-rows x BK=64 keys per tile, 256 threads = 16x16 thread grid.
// Thread (ty,tx) owns a 4x4 score tile and a 4x4 output tile.  Transposed
// LDS layouts give 16 FMAs per 2 LDS b128 reads.
// ---------------------------------------------------------------------------
constexpr int BQ = 64;
constexpr int BK = 64;

__global__ __launch_bounds__(256) void attn_kernel(
    const float* __restrict__ q,
    const float* __restrict__ k,
    const float* __restrict__ v,
    float* __restrict__ po,     // [ns][N][64] unnormalized partial out
    float* __restrict__ pm,     // [ns][N] running max
    float* __restrict__ pl,     // [ns][N] running sum
    int keys_per_split)
{
    __shared__ float qT[64][68];   // [dim][q-row]
    __shared__ float kT[64][68];   // [dim][k-col]
    __shared__ float pT[64][68];   // [k-col][q-row]
    __shared__ float vs[64 * 64];  // [key][v-dim] linear

    const int tid = threadIdx.x;
    const int tx  = tid & 15;
    const int ty  = tid >> 4;      // each ty-group (16 lanes) is wave-local
    const int qrow0 = blockIdx.x * BQ;
    const int split = blockIdx.y;
    const int key0  = split * keys_per_split;
    const int nt    = keys_per_split / BK;

    // stage qT (transpose): 64 rows x 16 float4 = 1024 float4, 4 per thread
#pragma unroll
    for (int it = 0; it < 4; ++it) {
        int f4  = tid + it * 256;
        int row = f4 >> 4;          // 0..63
        int c4  = f4 & 15;          // 0..15
        float4 t = *reinterpret_cast<const float4*>(
            q + (size_t)(qrow0 + row) * DKQ + c4 * 4);
        qT[c4 * 4 + 0][row] = t.x;
        qT[c4 * 4 + 1][row] = t.y;
        qT[c4 * 4 + 2][row] = t.z;
        qT[c4 * 4 + 3][row] = t.w;
    }

    float m[4], l[4], o[4][4];
#pragma unroll
    for (int i = 0; i < 4; ++i) {
        m[i] = -INFINITY; l[i] = 0.f;
#pragma unroll
        for (int j = 0; j < 4; ++j) o[i][j] = 0.f;
    }

    for (int t = 0; t < nt; ++t) {
        __syncthreads();   // covers qT staging (t=0) and prev-iter kT/vs reads
        // stage kT (transpose): 1024 float4, 4 per thread
#pragma unroll
        for (int it = 0; it < 4; ++it) {
            int f4  = tid + it * 256;
            int row = f4 >> 4;
            int c4  = f4 & 15;
            float4 tk = *reinterpret_cast<const float4*>(
                k + (size_t)(key0 + t * BK + row) * DKQ + c4 * 4);
            kT[c4 * 4 + 0][row] = tk.x;
            kT[c4 * 4 + 1][row] = tk.y;
            kT[c4 * 4 + 2][row] = tk.z;
            kT[c4 * 4 + 3][row] = tk.w;
        }
        // stage vs (linear copy, coalesced, 2-way banks)
        {
            const float* vg = v + (size_t)(key0 + t * BK) * DV;
#pragma unroll
            for (int it = 0; it < 4; ++it) {
                int f4 = tid + it * 256;
                *reinterpret_cast<float4*>(vs + f4 * 4) =
                    *reinterpret_cast<const float4*>(vg + f4 * 4);
            }
        }
        __syncthreads();

        // ---- QK^T : 4x4 register tile ----
        float s4[4][4];
#pragma unroll
        for (int i = 0; i < 4; ++i)
#pragma unroll
            for (int j = 0; j < 4; ++j) s4[i][j] = 0.f;

#pragma unroll 8
        for (int d = 0; d < 64; ++d) {
            float4 qv = *reinterpret_cast<const float4*>(&qT[d][4 * ty]);
            float4 kv = *reinterpret_cast<const float4*>(&kT[d][4 * tx]);
            float qa[4] = {qv.x, qv.y, qv.z, qv.w};
            float ka[4] = {kv.x, kv.y, kv.z, kv.w};
#pragma unroll
            for (int i = 0; i < 4; ++i)
#pragma unroll
                for (int j = 0; j < 4; ++j)
                    s4[i][j] += qa[i] * ka[j];
        }

        // ---- online softmax (row groups = 16 lanes, in-wave) ----
#pragma unroll
        for (int i = 0; i < 4; ++i) {
            float a = fmaxf(fmaxf(s4[i][0], s4[i][1]), fmaxf(s4[i][2], s4[i][3]));
            a *= 0.125f;
#pragma unroll
            for (int w2 = 1; w2 < 16; w2 <<= 1)
                a = fmaxf(a, __shfl_xor(a, w2, 16));
            float mn   = fmaxf(m[i], a);
            float corr = __expf(m[i] - mn);   // exp(-inf)=0 on first tile
            m[i] = mn;
            float ps = 0.f;
#pragma unroll
            for (int j = 0; j < 4; ++j) {
                float e = __expf(s4[i][j] * 0.125f - mn);
                s4[i][j] = e;
                ps += e;
            }
#pragma unroll
            for (int w2 = 1; w2 < 16; w2 <<= 1)
                ps += __shfl_xor(ps, w2, 16);
            l[i] = l[i] * corr + ps;
#pragma unroll
            for (int j = 0; j < 4; ++j) o[i][j] *= corr;
        }

        // write p transposed; readers are in the same 16-lane group -> no barrier
#pragma unroll
        for (int j = 0; j < 4; ++j) {
            float4 pv = {s4[0][j], s4[1][j], s4[2][j], s4[3][j]};
            *reinterpret_cast<float4*>(&pT[4 * tx + j][4 * ty]) = pv;
        }

        // ---- PV : 4x4 register tile ----
#pragma unroll 8
        for (int j = 0; j < 64; ++j) {
            float4 pv = *reinterpret_cast<const float4*>(&pT[j][4 * ty]);
            float4 vv = *reinterpret_cast<const float4*>(&vs[j * 64 + 4 * tx]);
            float pa[4] = {pv.x, pv.y, pv.z, pv.w};
            float va[4] = {vv.x, vv.y, vv.z, vv.w};
#pragma unroll
            for (int i = 0; i < 4; ++i)
#pragma unroll
                for (int jj = 0; jj < 4; ++jj)
                    o[i][jj] += pa[i] * va[jj];
        }
    }

    // epilogue: store unnormalized partials
    const size_t prow = (size_t)split * N + qrow0;
#pragma unroll
    for (int i = 0; i < 4; ++i) {
        float4 ov = {o[i][0], o[i][1], o[i][2], o[i][3]};
        *reinterpret_cast<float4*>(po + (prow + 4 * ty + i) * 64 + 4 * tx) = ov;
    }
    if (tx == 0) {
#pragma unroll
        for (int i = 0; i < 4; ++i) {
            pm[prow + 4 * ty + i] = m[i];
            pl[prow + 4 * ty + i] = l[i];
        }
    }
}

// ---------------------------------------------------------------------------
// Combine split-K partials: out = sum_s w_s*o_s / sum_s w_s*l_s
// 16 rows/block, 16 threads per row (c4 = 0..15 covers all 64 columns).
// ---------------------------------------------------------------------------
__global__ __launch_bounds__(256) void combine_kernel(
    const float* __restrict__ po,
    const float* __restrict__ pm,
    const float* __restrict__ pl,
    float* __restrict__ out, int ns)
{
    const int tid = threadIdx.x;
    const int row = blockIdx.x * 16 + (tid >> 4);
    const int c4  = tid & 15;

    float M = -INFINITY;
    for (int s = 0; s < ns; ++s)
        M = fmaxf(M, pm[(size_t)s * N + row]);
    float L = 0.f;
    float4 acc = {0.f, 0.f, 0.f, 0.f};
    for (int s = 0; s < ns; ++s) {
        float w = __expf(pm[(size_t)s * N + row] - M);
        L += w * pl[(size_t)s * N + row];
        float4 ov = *reinterpret_cast<const float4*>(
            po + ((size_t)s * N + row) * 64 + c4 * 4);
        acc.x += w * ov.x; acc.y += w * ov.y;
        acc.z += w * ov.z; acc.w += w * ov.w;
    }
    float inv = 1.f / L;
    float4 res = {acc.x * inv, acc.y * inv, acc.z * inv, acc.w * inv};
    *reinterpret_cast<float4*>(out + (size_t)row * 64 + c4 * 4) = res;
}

// ---------------------------------------------------------------------------
extern "C" void kernel_launch(void* const* d_in, const int* in_sizes, int n_in,
                              void* d_out, int out_size, void* d_ws, size_t ws_size,
                              hipStream_t stream)
{
    const float* x  = (const float*)d_in[0];
    const float* wq = (const float*)d_in[1];
    const float* wk = (const float*)d_in[2];
    const float* wv = (const float*)d_in[3];
    float* out = (float*)d_out;

    // workspace layout
    const size_t qkv_f = (size_t)3 * N * 64;            // 6 MB
    int ns = 4;
    while (ns > 1 &&
           (qkv_f + (size_t)ns * (N * 64 + 2 * N)) * sizeof(float) > ws_size)
        ns >>= 1;

    float* q  = (float*)d_ws;
    float* k  = q + (size_t)N * 64;
    float* v  = k + (size_t)N * 64;
    float* po = v + (size_t)N * 64;
    float* pm = po + (size_t)ns * N * 64;
    float* pl = pm + (size_t)ns * N;

    proj_kernel<<<N / 16, 192, 0, stream>>>(x, wq, wk, wv, q, k, v);

    dim3 agrid(N / BQ, ns);
    attn_kernel<<<agrid, 256, 0, stream>>>(q, k, v, po, pm, pl, N / ns);

    combine_kernel<<<N / 16, 256, 0, stream>>>(po, pm, pl, out, ns);
}

// Round 5
// 297.368 us; speedup vs baseline: 1.8917x; 1.4269x over previous
//
#include <hip/hip_runtime.h>
#include <hip/hip_bf16.h>
#include <math.h>

constexpr int N    = 8192;
constexpr int DIM  = 1024;
constexpr int DKQ  = 64;
constexpr int DV   = 64;

typedef __attribute__((ext_vector_type(8))) short bf16x8;   // 8 bf16 (4 VGPRs)
typedef __attribute__((ext_vector_type(4))) float f32x4;    // MFMA C/D

__device__ inline unsigned short f2bf(float f) {            // RN-even fp32->bf16
    unsigned u = __float_as_uint(f);
    u += 0x7fffu + ((u >> 16) & 1u);
    return (unsigned short)(u >> 16);
}
__device__ inline float bf2f(unsigned short h) {
    return __uint_as_float((unsigned)h << 16);
}

// ---------------------------------------------------------------------------
// Projection q|k|v = x @ w. 512 blocks x 192 thr; wave g owns matrix g,
// thread owns 16 rows x 1 col. Inner loop blocked by 4 dims: 16 b128
// broadcast xs reads + 4 w reads per 64 FMA -> VALU-bound.
// Epilogue writes SPLIT BF16 planes:
//   qhi/qlo[8192][64] row-major
//   khi/klo[8192][64] row-major, 16B-chunk XOR-swizzled: col ^= (row&7)<<3
//   vThi/vTlo[64][8192] transposed, swizzled: key-chunk ^= (dim&7)
// so attention stages tiles with plain linear 16B copies.
// ---------------------------------------------------------------------------
__global__ __launch_bounds__(192) void proj_kernel(
    const float* __restrict__ x,
    const float* __restrict__ wq,
    const float* __restrict__ wk,
    const float* __restrict__ wv,
    unsigned short* __restrict__ qhi, unsigned short* __restrict__ qlo,
    unsigned short* __restrict__ khi, unsigned short* __restrict__ klo,
    unsigned short* __restrict__ vthi, unsigned short* __restrict__ vtlo)
{
    __shared__ float xs[16][64];
    __shared__ float wls[3][64][64];

    const int tid = threadIdx.x;       // 0..191
    const int g   = tid >> 6;          // wave id = matrix id
    const int cc  = tid & 63;
    const int row0 = blockIdx.x * 16;

    float acc[16];
#pragma unroll
    for (int r = 0; r < 16; ++r) acc[r] = 0.f;

    for (int kc = 0; kc < DIM / 64; ++kc) {
        __syncthreads();
#pragma unroll
        for (int it = 0; it < 6; ++it) {
            int idx = tid + it * 192;
            if (idx < 1024)
                xs[idx >> 6][idx & 63] =
                    x[(size_t)(row0 + (idx >> 6)) * DIM + kc * 64 + (idx & 63)];
        }
#pragma unroll
        for (int it = 0; it < 16; ++it) {
            int f4  = tid + it * 192;
            int mg  = f4 >> 10;
            int off = f4 & 1023;
            const float* wsrc = (mg == 0) ? wq : (mg == 1) ? wk : wv;
            *reinterpret_cast<float4*>(&wls[mg][0][0] + off * 4) =
                *reinterpret_cast<const float4*>(wsrc + (size_t)kc * 4096 + off * 4);
        }
        __syncthreads();

#pragma unroll 4
        for (int d4 = 0; d4 < 16; ++d4) {
            float wv0 = wls[g][4 * d4 + 0][cc];
            float wv1 = wls[g][4 * d4 + 1][cc];
            float wv2 = wls[g][4 * d4 + 2][cc];
            float wv3 = wls[g][4 * d4 + 3][cc];
#pragma unroll
            for (int r = 0; r < 16; ++r) {
                float4 xv = *reinterpret_cast<const float4*>(&xs[r][4 * d4]);
                acc[r] += xv.x * wv0 + xv.y * wv1 + xv.z * wv2 + xv.w * wv3;
            }
        }
    }

    if (g == 0) {
#pragma unroll
        for (int r = 0; r < 16; ++r) {
            int row = row0 + r;
            unsigned short h = f2bf(acc[r]);
            qhi[(size_t)row * 64 + cc] = h;
            qlo[(size_t)row * 64 + cc] = f2bf(acc[r] - bf2f(h));
        }
    } else if (g == 1) {
#pragma unroll
        for (int r = 0; r < 16; ++r) {
            int row = row0 + r;
            int ci  = cc ^ ((row & 7) << 3);          // baked swizzle
            unsigned short h = f2bf(acc[r]);
            khi[(size_t)row * 64 + ci] = h;
            klo[(size_t)row * 64 + ci] = f2bf(acc[r] - bf2f(h));
        }
    } else {
        // vT planes: dim = cc, keys row0..row0+15, two 16B chunks
#pragma unroll
        for (int half = 0; half < 2; ++half) {
            unsigned uh[4], ul[4];
#pragma unroll
            for (int p = 0; p < 4; ++p) {
                float f0 = acc[half * 8 + 2 * p];
                float f1 = acc[half * 8 + 2 * p + 1];
                unsigned short h0 = f2bf(f0), h1 = f2bf(f1);
                unsigned short l0 = f2bf(f0 - bf2f(h0)), l1 = f2bf(f1 - bf2f(h1));
                uh[p] = (unsigned)h0 | ((unsigned)h1 << 16);
                ul[p] = (unsigned)l0 | ((unsigned)l1 << 16);
            }
            int cg  = (row0 >> 3) + half;
            int cgs = (cg & ~7) | ((cg & 7) ^ (cc & 7));   // baked swizzle
            size_t idx = (size_t)cc * 8192 + (size_t)cgs * 8;
            uint4 vh = {uh[0], uh[1], uh[2], uh[3]};
            uint4 vl = {ul[0], ul[1], ul[2], ul[3]};
            *reinterpret_cast<uint4*>(vthi + idx) = vh;
            *reinterpret_cast<uint4*>(vtlo + idx) = vl;
        }
    }
}

// ---------------------------------------------------------------------------
// Flash attention via split-bf16 MFMA (3-term: hihi+hilo+lohi, err ~2^-16).
// 256 thr = 4 waves; wave w owns q-rows qrow0+16w..+15; BK=64 keys/tile.
// Q frags in registers; K/vT tiles staged linearly (swizzle pre-baked).
// Softmax on C-layout: lane holds rows 4*(lane>>4)+r, col lane&15 (m89).
// ---------------------------------------------------------------------------
constexpr int BQ = 64;
constexpr int BK = 64;

__global__ __launch_bounds__(256) void attn_kernel(
    const unsigned short* __restrict__ qhi, const unsigned short* __restrict__ qlo,
    const unsigned short* __restrict__ khi, const unsigned short* __restrict__ klo,
    const unsigned short* __restrict__ vthi, const unsigned short* __restrict__ vtlo,
    float* __restrict__ po, float* __restrict__ pm, float* __restrict__ pl,
    int keys_per_split)
{
    __shared__ unsigned short stage[16384];        // 32KB: khi|klo|vthi|vtlo 8KB each
    __shared__ unsigned short pThi[4][16][72];
    __shared__ unsigned short pTlo[4][16][72];

    const int tid  = threadIdx.x;
    const int lane = tid & 63;
    const int w    = tid >> 6;
    const int g16  = lane >> 4;      // 0..3
    const int i16  = lane & 15;
    const int qrow0 = blockIdx.x * BQ;
    const int split = blockIdx.y;
    const int key0  = split * keys_per_split;
    const int nt    = keys_per_split / BK;

    // Q fragments (registers, whole kernel): A[i16][32c + 8*g16 + e]
    bf16x8 qh[2], ql[2];
    {
        const size_t qr = (size_t)(qrow0 + w * 16 + i16) * 64;
#pragma unroll
        for (int c = 0; c < 2; ++c) {
            qh[c] = *reinterpret_cast<const bf16x8*>(qhi + qr + c * 32 + g16 * 8);
            ql[c] = *reinterpret_cast<const bf16x8*>(qlo + qr + c * 32 + g16 * 8);
        }
    }

    float m_r[4], l_r[4];
    f32x4 o_acc[4];
#pragma unroll
    for (int r = 0; r < 4; ++r) { m_r[r] = -INFINITY; l_r[r] = 0.f; }
#pragma unroll
    for (int db = 0; db < 4; ++db) o_acc[db] = {0.f, 0.f, 0.f, 0.f};

    for (int t = 0; t < nt; ++t) {
        const int key0t = key0 + t * BK;
        __syncthreads();
        // stage 32KB linearly: 8 x 16B per thread (swizzle baked in source)
#pragma unroll
        for (int u = 0; u < 8; ++u) {
            int o   = u * 4096 + tid * 16;           // byte offset in stage
            int row = ((u & 1) << 5) + (tid >> 3);   // 0..63
            int ch  = tid & 7;
            const unsigned short* src;
            if (u < 2)      src = khi  + (size_t)(key0t + row) * 64 + ch * 8;
            else if (u < 4) src = klo  + (size_t)(key0t + row) * 64 + ch * 8;
            else if (u < 6) src = vthi + (size_t)row * 8192 + key0t + ch * 8;
            else            src = vtlo + (size_t)row * 8192 + key0t + ch * 8;
            *reinterpret_cast<uint4*>(reinterpret_cast<char*>(stage) + o) =
                *reinterpret_cast<const uint4*>(src);
        }
        __syncthreads();

        // ---- QK^T: 4 col-tiles x 2 k-chunks x 3 split-terms ----
        f32x4 sacc[4];
#pragma unroll
        for (int j = 0; j < 4; ++j) {
            f32x4 a = {0.f, 0.f, 0.f, 0.f};
#pragma unroll
            for (int c = 0; c < 2; ++c) {
                const int kr    = 16 * j + i16;
                const int byteO = ((kr * 128 + c * 64 + g16 * 16) ^ ((kr & 7) << 4));
                bf16x8 kh = *reinterpret_cast<const bf16x8*>(
                    reinterpret_cast<const char*>(stage) + byteO);
                bf16x8 kl = *reinterpret_cast<const bf16x8*>(
                    reinterpret_cast<const char*>(stage) + byteO + 8192);
                a = __builtin_amdgcn_mfma_f32_16x16x32_bf16(qh[c], kh, a, 0, 0, 0);
                a = __builtin_amdgcn_mfma_f32_16x16x32_bf16(qh[c], kl, a, 0, 0, 0);
                a = __builtin_amdgcn_mfma_f32_16x16x32_bf16(ql[c], kh, a, 0, 0, 0);
            }
            sacc[j] = a;
        }

        // ---- online softmax; lane's rows: 4*g16 + r ----
        float p4[4][4];   // [j][r]
        float corrv[4];
#pragma unroll
        for (int r = 0; r < 4; ++r) {
            float a = fmaxf(fmaxf(sacc[0][r], sacc[1][r]),
                            fmaxf(sacc[2][r], sacc[3][r])) * 0.125f;
#pragma unroll
            for (int msk = 1; msk < 16; msk <<= 1)
                a = fmaxf(a, __shfl_xor(a, msk, 16));
            float mn   = fmaxf(m_r[r], a);
            float corr = __expf(m_r[r] - mn);
            m_r[r] = mn;
            corrv[r] = corr;
            float ps = 0.f;
#pragma unroll
            for (int j = 0; j < 4; ++j) {
                float e = __expf(sacc[j][r] * 0.125f - mn);
                p4[j][r] = e;
                ps += e;
            }
#pragma unroll
            for (int msk = 1; msk < 16; msk <<= 1)
                ps += __shfl_xor(ps, msk, 16);
            l_r[r] = l_r[r] * corr + ps;
        }
        {
            f32x4 cv = {corrv[0], corrv[1], corrv[2], corrv[3]};
#pragma unroll
            for (int db = 0; db < 4; ++db) o_acc[db] *= cv;
        }

        // ---- split P into per-wave LDS planes (same-wave consumer) ----
#pragma unroll
        for (int j = 0; j < 4; ++j)
#pragma unroll
            for (int r = 0; r < 4; ++r) {
                unsigned short h = f2bf(p4[j][r]);
                pThi[w][4 * g16 + r][16 * j + i16] = h;
                pTlo[w][4 * g16 + r][16 * j + i16] = f2bf(p4[j][r] - bf2f(h));
            }

        // ---- PV: O[16q][16d-block] over 2 key-chunks x 3 terms ----
        bf16x8 ph[2], pql[2];
#pragma unroll
        for (int c = 0; c < 2; ++c) {
            ph[c]  = *reinterpret_cast<const bf16x8*>(&pThi[w][i16][32 * c + 8 * g16]);
            pql[c] = *reinterpret_cast<const bf16x8*>(&pTlo[w][i16][32 * c + 8 * g16]);
        }
#pragma unroll
        for (int db = 0; db < 4; ++db) {
            f32x4 a = o_acc[db];
#pragma unroll
            for (int c = 0; c < 2; ++c) {
                const int vr    = 16 * db + i16;
                const int byteO = ((vr * 128 + c * 64 + g16 * 16) ^ ((vr & 7) << 4)) + 16384;
                bf16x8 vh = *reinterpret_cast<const bf16x8*>(
                    reinterpret_cast<const char*>(stage) + byteO);
                bf16x8 vl = *reinterpret_cast<const bf16x8*>(
                    reinterpret_cast<const char*>(stage) + byteO + 8192);
                a = __builtin_amdgcn_mfma_f32_16x16x32_bf16(ph[c],  vh, a, 0, 0, 0);
                a = __builtin_amdgcn_mfma_f32_16x16x32_bf16(ph[c],  vl, a, 0, 0, 0);
                a = __builtin_amdgcn_mfma_f32_16x16x32_bf16(pql[c], vh, a, 0, 0, 0);
            }
            o_acc[db] = a;
        }
    }

    // epilogue: unnormalized partials + m/l
    const size_t prow = (size_t)split * N + qrow0 + w * 16;
#pragma unroll
    for (int db = 0; db < 4; ++db)
#pragma unroll
        for (int r = 0; r < 4; ++r)
            po[(prow + 4 * g16 + r) * 64 + 16 * db + i16] = o_acc[db][r];
    if (i16 == 0) {
#pragma unroll
        for (int r = 0; r < 4; ++r) {
            pm[prow + 4 * g16 + r] = m_r[r];
            pl[prow + 4 * g16 + r] = l_r[r];
        }
    }
}

// ---------------------------------------------------------------------------
// Combine split-K partials: out = sum_s w_s*o_s / sum_s w_s*l_s
// ---------------------------------------------------------------------------
__global__ __launch_bounds__(256) void combine_kernel(
    const float* __restrict__ po,
    const float* __restrict__ pm,
    const float* __restrict__ pl,
    float* __restrict__ out, int ns)
{
    const int tid = threadIdx.x;
    const int row = blockIdx.x * 16 + (tid >> 4);
    const int c4  = tid & 15;

    float M = -INFINITY;
    for (int s = 0; s < ns; ++s)
        M = fmaxf(M, pm[(size_t)s * N + row]);
    float L = 0.f;
    float4 acc = {0.f, 0.f, 0.f, 0.f};
    for (int s = 0; s < ns; ++s) {
        float ws = __expf(pm[(size_t)s * N + row] - M);
        L += ws * pl[(size_t)s * N + row];
        float4 ov = *reinterpret_cast<const float4*>(
            po + ((size_t)s * N + row) * 64 + c4 * 4);
        acc.x += ws * ov.x; acc.y += ws * ov.y;
        acc.z += ws * ov.z; acc.w += ws * ov.w;
    }
    float inv = 1.f / L;
    float4 res = {acc.x * inv, acc.y * inv, acc.z * inv, acc.w * inv};
    *reinterpret_cast<float4*>(out + (size_t)row * 64 + c4 * 4) = res;
}

// ---------------------------------------------------------------------------
extern "C" void kernel_launch(void* const* d_in, const int* in_sizes, int n_in,
                              void* d_out, int out_size, void* d_ws, size_t ws_size,
                              hipStream_t stream)
{
    const float* x  = (const float*)d_in[0];
    const float* wq = (const float*)d_in[1];
    const float* wk = (const float*)d_in[2];
    const float* wv = (const float*)d_in[3];
    float* out = (float*)d_out;

    const size_t PLANE = (size_t)N * 64;           // ushorts per plane
    unsigned short* qhi  = (unsigned short*)d_ws;
    unsigned short* qlo  = qhi + PLANE;
    unsigned short* khi  = qlo + PLANE;
    unsigned short* klo  = khi + PLANE;
    unsigned short* vthi = klo + PLANE;
    unsigned short* vtlo = vthi + PLANE;
    const size_t plane_bytes = 6 * PLANE * 2;      // 6 MB

    int ns = 8;
    while (ns > 1 &&
           plane_bytes + (size_t)ns * ((size_t)N * 64 * 4 + (size_t)N * 8) > ws_size)
        ns >>= 1;

    float* po = (float*)((char*)d_ws + plane_bytes);
    float* pm = po + (size_t)ns * N * 64;
    float* pl = pm + (size_t)ns * N;

    proj_kernel<<<N / 16, 192, 0, stream>>>(x, wq, wk, wv,
                                            qhi, qlo, khi, klo, vthi, vtlo);

    dim3 agrid(N / BQ, ns);
    attn_kernel<<<agrid, 256, 0, stream>>>(qhi, qlo, khi, klo, vthi, vtlo,
                                           po, pm, pl, N / ns);

    combine_kernel<<<N / 16, 256, 0, stream>>>(po, pm, pl, out, ns);
}

// Round 6
// 147.175 us; speedup vs baseline: 3.8222x; 2.0205x over previous
//
#include <hip/hip_runtime.h>
#include <hip/hip_bf16.h>
#include <math.h>

constexpr int N    = 8192;
constexpr int DIM  = 1024;

typedef __attribute__((ext_vector_type(8))) short bf16x8;   // 8 bf16 (4 VGPRs)
typedef __attribute__((ext_vector_type(4))) float f32x4;    // MFMA C/D

__device__ inline unsigned short f2bf(float f) {            // RN-even fp32->bf16
    unsigned u = __float_as_uint(f);
    u += 0x7fffu + ((u >> 16) & 1u);
    return (unsigned short)(u >> 16);
}
__device__ inline float bf2f(unsigned short h) {
    return __uint_as_float((unsigned)h << 16);
}

// ---------------------------------------------------------------------------
// prep_w: transpose + split w{q,k,v}[1024][64] into wT hi/lo planes [192][1024]
// (row c = g*64 + col). Tiny one-shot kernel; gather reads, coalesced writes.
// ---------------------------------------------------------------------------
__global__ __launch_bounds__(256) void prep_w_kernel(
    const float* __restrict__ wq, const float* __restrict__ wk,
    const float* __restrict__ wv,
    unsigned short* __restrict__ wthi, unsigned short* __restrict__ wtlo)
{
    int idx = blockIdx.x * 256 + threadIdx.x;     // 0..196607
    int c   = idx >> 10;                          // 0..191
    int k   = idx & 1023;
    const float* wsrc = (c < 64) ? wq : (c < 128) ? wk : wv;
    float f = wsrc[(size_t)k * 64 + (c & 63)];
    unsigned short h = f2bf(f);
    wthi[idx] = h;
    wtlo[idx] = f2bf(f - bf2f(h));
}

// ---------------------------------------------------------------------------
// Projection via split-bf16 MFMA (3-term). 256 blocks x 512 thr (8 waves).
// Block = 32 rows x all 192 cols; wave w: row-tile w>>2, col-tiles (w&3)*3..+2.
// x tile converted to XOR-swizzled split-bf16 LDS (double-buffered, 1 barrier
// per iter, float4 preload hides HBM). B-frags straight from L2 (wT planes).
// Epilogue writes the attn-ready planes (same layouts/swizzles as round 5).
// ---------------------------------------------------------------------------
__global__ __launch_bounds__(512) void proj_kernel(
    const float* __restrict__ x,
    const unsigned short* __restrict__ wthi,
    const unsigned short* __restrict__ wtlo,
    unsigned short* __restrict__ qhi, unsigned short* __restrict__ qlo,
    unsigned short* __restrict__ khi, unsigned short* __restrict__ klo,
    unsigned short* __restrict__ vthi)
{
    __shared__ unsigned short xs[2][2][2048];   // [buf][hi/lo][32 rows * 64 k]

    const int tid  = threadIdx.x;
    const int lane = tid & 63;
    const int w    = tid >> 6;            // 0..7
    const int g16  = lane >> 4;
    const int i16  = lane & 15;
    const int rt   = w >> 2;              // row-tile 0..1
    const int ct0  = (w & 3) * 3;         // col-tiles ct0..ct0+2
    const int row0 = blockIdx.x * 32;

    const int xr   = tid >> 4;            // 0..31 (staging row)
    const int xc4  = tid & 15;            // float4 index within 64-k chunk
    const int xoff = xr * 64 + (((xc4 >> 1) ^ (xr & 7)) << 3) + ((xc4 & 1) << 2);
    const int arow = rt * 16 + i16;

    f32x4 acc[3];
    acc[0] = acc[1] = acc[2] = (f32x4){0.f, 0.f, 0.f, 0.f};

    float4 xn = *reinterpret_cast<const float4*>(
        x + (size_t)(row0 + xr) * DIM + xc4 * 4);

    for (int t = 0; t < 16; ++t) {
        const int b = t & 1;
        {   // convert + swizzled LDS write (4 elems -> 8B per plane)
            unsigned short h0 = f2bf(xn.x), h1 = f2bf(xn.y),
                           h2 = f2bf(xn.z), h3 = f2bf(xn.w);
            unsigned short l0 = f2bf(xn.x - bf2f(h0)), l1 = f2bf(xn.y - bf2f(h1)),
                           l2 = f2bf(xn.z - bf2f(h2)), l3 = f2bf(xn.w - bf2f(h3));
            uint2 uh = { (unsigned)h0 | ((unsigned)h1 << 16),
                         (unsigned)h2 | ((unsigned)h3 << 16) };
            uint2 ul = { (unsigned)l0 | ((unsigned)l1 << 16),
                         (unsigned)l2 | ((unsigned)l3 << 16) };
            *reinterpret_cast<uint2*>(&xs[b][0][xoff]) = uh;
            *reinterpret_cast<uint2*>(&xs[b][1][xoff]) = ul;
        }
        __syncthreads();
        if (t < 15)
            xn = *reinterpret_cast<const float4*>(
                x + (size_t)(row0 + xr) * DIM + (t + 1) * 64 + xc4 * 4);

        // B fragments from L2 (pre-transposed split planes)
        bf16x8 bh[3][2], bl[3][2];
#pragma unroll
        for (int ct = 0; ct < 3; ++ct)
#pragma unroll
            for (int kc = 0; kc < 2; ++kc) {
                size_t wof = (size_t)((ct0 + ct) * 16 + i16) * 1024
                           + t * 64 + kc * 32 + g16 * 8;
                bh[ct][kc] = *reinterpret_cast<const bf16x8*>(wthi + wof);
                bl[ct][kc] = *reinterpret_cast<const bf16x8*>(wtlo + wof);
            }
        // A fragments from LDS (XOR-swizzled chunks)
        bf16x8 ah[2], al[2];
#pragma unroll
        for (int kc = 0; kc < 2; ++kc) {
            int aoff = arow * 64 + ((((kc << 2) + g16) ^ (arow & 7)) << 3);
            ah[kc] = *reinterpret_cast<const bf16x8*>(&xs[b][0][aoff]);
            al[kc] = *reinterpret_cast<const bf16x8*>(&xs[b][1][aoff]);
        }
#pragma unroll
        for (int ct = 0; ct < 3; ++ct)
#pragma unroll
            for (int kc = 0; kc < 2; ++kc) {
                acc[ct] = __builtin_amdgcn_mfma_f32_16x16x32_bf16(
                              ah[kc], bh[ct][kc], acc[ct], 0, 0, 0);
                acc[ct] = __builtin_amdgcn_mfma_f32_16x16x32_bf16(
                              ah[kc], bl[ct][kc], acc[ct], 0, 0, 0);
                acc[ct] = __builtin_amdgcn_mfma_f32_16x16x32_bf16(
                              al[kc], bh[ct][kc], acc[ct], 0, 0, 0);
            }
    }

    // epilogue: write attn-ready split planes (swizzles baked, round-5 format)
#pragma unroll
    for (int ct = 0; ct < 3; ++ct) {
        int cglob = (ct0 + ct) * 16 + i16;
        int g   = cglob >> 6;
        int c64 = cglob & 63;
#pragma unroll
        for (int rr = 0; rr < 4; ++rr) {
            int row = row0 + rt * 16 + 4 * g16 + rr;
            float f = acc[ct][rr];
            unsigned short h  = f2bf(f);
            unsigned short lo = f2bf(f - bf2f(h));
            if (g == 0) {
                qhi[(size_t)row * 64 + c64] = h;
                qlo[(size_t)row * 64 + c64] = lo;
            } else if (g == 1) {
                int ci = c64 ^ ((row & 7) << 3);
                khi[(size_t)row * 64 + ci] = h;
                klo[(size_t)row * 64 + ci] = lo;
            } else {
                int cg  = row >> 3;
                int cgs = (cg & ~7) | ((cg & 7) ^ (c64 & 7));
                vthi[(size_t)c64 * 8192 + cgs * 8 + (row & 7)] = h;
            }
        }
    }
}

// ---------------------------------------------------------------------------
// Flash attention. QK^T split-bf16 3-term (scores need ~2^-16); PV 1-term
// plain bf16 (convex average, error ~0.3 max). 4 waves x 16 q-rows, BK=64.
// ---------------------------------------------------------------------------
constexpr int BQ = 64;
constexpr int BK = 64;

__global__ __launch_bounds__(256) void attn_kernel(
    const unsigned short* __restrict__ qhi, const unsigned short* __restrict__ qlo,
    const unsigned short* __restrict__ khi, const unsigned short* __restrict__ klo,
    const unsigned short* __restrict__ vthi,
    float* __restrict__ po, float* __restrict__ pm, float* __restrict__ pl,
    int keys_per_split)
{
    __shared__ unsigned short stage[12288];        // 24KB: khi|klo|vthi 8KB each
    __shared__ unsigned short pThi[4][16][72];

    const int tid  = threadIdx.x;
    const int lane = tid & 63;
    const int w    = tid >> 6;
    const int g16  = lane >> 4;
    const int i16  = lane & 15;
    const int qrow0 = blockIdx.x * BQ;
    const int split = blockIdx.y;
    const int key0  = split * keys_per_split;
    const int nt    = keys_per_split / BK;

    bf16x8 qh[2], ql[2];
    {
        const size_t qr = (size_t)(qrow0 + w * 16 + i16) * 64;
#pragma unroll
        for (int c = 0; c < 2; ++c) {
            qh[c] = *reinterpret_cast<const bf16x8*>(qhi + qr + c * 32 + g16 * 8);
            ql[c] = *reinterpret_cast<const bf16x8*>(qlo + qr + c * 32 + g16 * 8);
        }
    }

    float m_r[4], l_r[4];
    f32x4 o_acc[4];
#pragma unroll
    for (int r = 0; r < 4; ++r) { m_r[r] = -INFINITY; l_r[r] = 0.f; }
#pragma unroll
    for (int db = 0; db < 4; ++db) o_acc[db] = {0.f, 0.f, 0.f, 0.f};

    for (int t = 0; t < nt; ++t) {
        const int key0t = key0 + t * BK;
        __syncthreads();
        // stage 24KB linearly: 6 x 16B per thread (swizzles baked at write)
#pragma unroll
        for (int u = 0; u < 6; ++u) {
            int o   = u * 4096 + tid * 16;
            int row = ((u & 1) << 5) + (tid >> 3);
            int ch  = tid & 7;
            const unsigned short* src;
            if (u < 2)      src = khi  + (size_t)(key0t + row) * 64 + ch * 8;
            else if (u < 4) src = klo  + (size_t)(key0t + row) * 64 + ch * 8;
            else            src = vthi + (size_t)row * 8192 + key0t + ch * 8;
            *reinterpret_cast<uint4*>(reinterpret_cast<char*>(stage) + o) =
                *reinterpret_cast<const uint4*>(src);
        }
        __syncthreads();

        // ---- QK^T: 4 col-tiles x 2 k-chunks x 3 split-terms ----
        f32x4 sacc[4];
#pragma unroll
        for (int j = 0; j < 4; ++j) {
            f32x4 a = {0.f, 0.f, 0.f, 0.f};
#pragma unroll
            for (int c = 0; c < 2; ++c) {
                const int kr    = 16 * j + i16;
                const int byteO = ((kr * 128 + c * 64 + g16 * 16) ^ ((kr & 7) << 4));
                bf16x8 kh = *reinterpret_cast<const bf16x8*>(
                    reinterpret_cast<const char*>(stage) + byteO);
                bf16x8 kl = *reinterpret_cast<const bf16x8*>(
                    reinterpret_cast<const char*>(stage) + byteO + 8192);
                a = __builtin_amdgcn_mfma_f32_16x16x32_bf16(qh[c], kh, a, 0, 0, 0);
                a = __builtin_amdgcn_mfma_f32_16x16x32_bf16(qh[c], kl, a, 0, 0, 0);
                a = __builtin_amdgcn_mfma_f32_16x16x32_bf16(ql[c], kh, a, 0, 0, 0);
            }
            sacc[j] = a;
        }

        // ---- online softmax; lane's rows: 4*g16 + r ----
        float p4[4][4];
        float corrv[4];
#pragma unroll
        for (int r = 0; r < 4; ++r) {
            float a = fmaxf(fmaxf(sacc[0][r], sacc[1][r]),
                            fmaxf(sacc[2][r], sacc[3][r])) * 0.125f;
#pragma unroll
            for (int msk = 1; msk < 16; msk <<= 1)
                a = fmaxf(a, __shfl_xor(a, msk, 16));
            float mn   = fmaxf(m_r[r], a);
            float corr = __expf(m_r[r] - mn);
            m_r[r] = mn;
            corrv[r] = corr;
            float ps = 0.f;
#pragma unroll
            for (int j = 0; j < 4; ++j) {
                float e = __expf(sacc[j][r] * 0.125f - mn);
                p4[j][r] = e;
                ps += e;
            }
#pragma unroll
            for (int msk = 1; msk < 16; msk <<= 1)
                ps += __shfl_xor(ps, msk, 16);
            l_r[r] = l_r[r] * corr + ps;
        }
        {
            f32x4 cv = {corrv[0], corrv[1], corrv[2], corrv[3]};
#pragma unroll
            for (int db = 0; db < 4; ++db) o_acc[db] *= cv;
        }

        // ---- P (bf16) into per-wave LDS plane (same-wave consumer) ----
#pragma unroll
        for (int j = 0; j < 4; ++j)
#pragma unroll
            for (int r = 0; r < 4; ++r)
                pThi[w][4 * g16 + r][16 * j + i16] = f2bf(p4[j][r]);

        // ---- PV: 1-term bf16 over 2 key-chunks ----
        bf16x8 ph[2];
#pragma unroll
        for (int c = 0; c < 2; ++c)
            ph[c] = *reinterpret_cast<const bf16x8*>(&pThi[w][i16][32 * c + 8 * g16]);
#pragma unroll
        for (int db = 0; db < 4; ++db) {
            f32x4 a = o_acc[db];
#pragma unroll
            for (int c = 0; c < 2; ++c) {
                const int vr    = 16 * db + i16;
                const int byteO = ((vr * 128 + c * 64 + g16 * 16) ^ ((vr & 7) << 4)) + 16384;
                bf16x8 vh = *reinterpret_cast<const bf16x8*>(
                    reinterpret_cast<const char*>(stage) + byteO);
                a = __builtin_amdgcn_mfma_f32_16x16x32_bf16(ph[c], vh, a, 0, 0, 0);
            }
            o_acc[db] = a;
        }
    }

    const size_t prow = (size_t)split * N + qrow0 + w * 16;
#pragma unroll
    for (int db = 0; db < 4; ++db)
#pragma unroll
        for (int r = 0; r < 4; ++r)
            po[(prow + 4 * g16 + r) * 64 + 16 * db + i16] = o_acc[db][r];
    if (i16 == 0) {
#pragma unroll
        for (int r = 0; r < 4; ++r) {
            pm[prow + 4 * g16 + r] = m_r[r];
            pl[prow + 4 * g16 + r] = l_r[r];
        }
    }
}

// ---------------------------------------------------------------------------
// Combine split-K partials: out = sum_s w_s*o_s / sum_s w_s*l_s
// ---------------------------------------------------------------------------
__global__ __launch_bounds__(256) void combine_kernel(
    const float* __restrict__ po,
    const float* __restrict__ pm,
    const float* __restrict__ pl,
    float* __restrict__ out, int ns)
{
    const int tid = threadIdx.x;
    const int row = blockIdx.x * 16 + (tid >> 4);
    const int c4  = tid & 15;

    float M = -INFINITY;
    for (int s = 0; s < ns; ++s)
        M = fmaxf(M, pm[(size_t)s * N + row]);
    float L = 0.f;
    float4 acc = {0.f, 0.f, 0.f, 0.f};
    for (int s = 0; s < ns; ++s) {
        float ws = __expf(pm[(size_t)s * N + row] - M);
        L += ws * pl[(size_t)s * N + row];
        float4 ov = *reinterpret_cast<const float4*>(
            po + ((size_t)s * N + row) * 64 + c4 * 4);
        acc.x += ws * ov.x; acc.y += ws * ov.y;
        acc.z += ws * ov.z; acc.w += ws * ov.w;
    }
    float inv = 1.f / L;
    float4 res = {acc.x * inv, acc.y * inv, acc.z * inv, acc.w * inv};
    *reinterpret_cast<float4*>(out + (size_t)row * 64 + c4 * 4) = res;
}

// ---------------------------------------------------------------------------
extern "C" void kernel_launch(void* const* d_in, const int* in_sizes, int n_in,
                              void* d_out, int out_size, void* d_ws, size_t ws_size,
                              hipStream_t stream)
{
    const float* x  = (const float*)d_in[0];
    const float* wq = (const float*)d_in[1];
    const float* wk = (const float*)d_in[2];
    const float* wv = (const float*)d_in[3];
    float* out = (float*)d_out;

    const size_t PLANE = (size_t)N * 64;               // ushorts per plane
    unsigned short* qhi  = (unsigned short*)d_ws;
    unsigned short* qlo  = qhi + PLANE;
    unsigned short* khi  = qlo + PLANE;
    unsigned short* klo  = khi + PLANE;
    unsigned short* vthi = klo + PLANE;
    const size_t plane_bytes = 5 * PLANE * 2;          // 5 MB
    const size_t wt_elems = (size_t)192 * 1024;
    const size_t wt_bytes = 2 * wt_elems * 2;          // 786 KB

    int ns = 8;
    while (ns > 1 &&
           plane_bytes + wt_bytes +
           (size_t)ns * ((size_t)N * 64 * 4 + (size_t)N * 8) > ws_size)
        ns >>= 1;

    float* po = (float*)((char*)d_ws + plane_bytes);
    float* pm = po + (size_t)ns * N * 64;
    float* pl = pm + (size_t)ns * N;
    unsigned short* wthi = (unsigned short*)(pl + (size_t)ns * N);
    unsigned short* wtlo = wthi + wt_elems;

    prep_w_kernel<<<768, 256, 0, stream>>>(wq, wk, wv, wthi, wtlo);
    proj_kernel<<<256, 512, 0, stream>>>(x, wthi, wtlo,
                                         qhi, qlo, khi, klo, vthi);
    dim3 agrid(N / BQ, ns);
    attn_kernel<<<agrid, 256, 0, stream>>>(qhi, qlo, khi, klo, vthi,
                                           po, pm, pl, N / ns);
    combine_kernel<<<N / 16, 256, 0, stream>>>(po, pm, pl, out, ns);
}

// Round 7
// 106.422 us; speedup vs baseline: 5.2858x; 1.3829x over previous
//
#include <hip/hip_runtime.h>
#include <hip/hip_bf16.h>
#include <math.h>

constexpr int N    = 8192;
constexpr int DIM  = 1024;

typedef __attribute__((ext_vector_type(8))) short bf16x8;   // 8 bf16 (4 VGPRs)
typedef __attribute__((ext_vector_type(4))) float f32x4;    // MFMA C/D

__device__ inline unsigned short f2bf(float f) {            // RN-even fp32->bf16
    unsigned u = __float_as_uint(f);
    u += 0x7fffu + ((u >> 16) & 1u);
    return (unsigned short)(u >> 16);
}
__device__ inline float bf2f(unsigned short h) {
    return __uint_as_float((unsigned)h << 16);
}
// async global->LDS, 16B per lane; dest must be wave-uniform base + lane*16
__device__ inline void gload16(const void* gsrc, void* ldst) {
    typedef __attribute__((address_space(1))) const unsigned int GU;
    typedef __attribute__((address_space(3))) unsigned int LU;
    __builtin_amdgcn_global_load_lds((GU*)gsrc, (LU*)ldst, 16, 0, 0);
}

// ---------------------------------------------------------------------------
// prep_w: transpose + split w into wT hi/lo planes [192][1024], with the
// proj B-fragment XOR swizzle BAKED into the k-order of each row:
// element (c,k) stored at c*1024 + (k&~63) + ((((k>>3)&7) ^ (c&7))<<3) + (k&7)
// so proj can stage with linear global_load_lds copies.
// ---------------------------------------------------------------------------
__global__ __launch_bounds__(256) void prep_w_kernel(
    const float* __restrict__ wq, const float* __restrict__ wk,
    const float* __restrict__ wv,
    unsigned short* __restrict__ wthi, unsigned short* __restrict__ wtlo)
{
    int idx = blockIdx.x * 256 + threadIdx.x;     // 0..196607
    int c   = idx >> 10;                          // 0..191
    int k   = idx & 1023;
    const float* wsrc = (c < 64) ? wq : (c < 128) ? wk : wv;
    float f = wsrc[(size_t)k * 64 + (c & 63)];
    unsigned short h = f2bf(f);
    int pos = c * 1024 + (k & ~63) + ((((k >> 3) & 7) ^ (c & 7)) << 3) + (k & 7);
    wthi[pos] = h;
    wtlo[pos] = f2bf(f - bf2f(h));
}

// ---------------------------------------------------------------------------
// Projection via split-bf16 MFMA (3-term). Grid 128x4 (row-block 64 rows x
// col-block 48 cols), 256 thr = 4 waves; wave w: rows w*16..+15, all 3
// col-tiles. A (x) converted to swizzled split-bf16 LDS; B staged via
// global_load_lds (swizzle pre-baked by prep_w). Double-buffered, B for t+1
// prefetched into the other buffer during MFMA of t.
// Epilogue writes attn-ready planes; q gets 0.125*log2e folded in.
// ---------------------------------------------------------------------------
__global__ __launch_bounds__(256) void proj_kernel(
    const float* __restrict__ x,
    const unsigned short* __restrict__ wthi,
    const unsigned short* __restrict__ wtlo,
    unsigned short* __restrict__ qhi, unsigned short* __restrict__ qlo,
    unsigned short* __restrict__ khi, unsigned short* __restrict__ klo,
    unsigned short* __restrict__ vthi)
{
    __shared__ unsigned short As[2][2][4096];   // [buf][hi/lo][64r*64k] 8KB planes
    __shared__ unsigned short Bs[2][2][3072];   // [buf][hi/lo][48c*64k] 6KB planes

    const int tid  = threadIdx.x;
    const int lane = tid & 63;
    const int w    = tid >> 6;
    const int g16  = lane >> 4;
    const int i16  = lane & 15;
    const int row0 = blockIdx.x * 64;
    const int col0 = blockIdx.y * 48;           // multiple of 8 -> swizzle safe

    float4 xn[4];
    auto loadX = [&](int t) {
#pragma unroll
        for (int i = 0; i < 4; ++i) {
            int f4 = i * 256 + tid;
            xn[i] = *reinterpret_cast<const float4*>(
                x + (size_t)(row0 + (f4 >> 4)) * DIM + t * 64 + (f4 & 15) * 4);
        }
    };
    auto stageB = [&](int t, int buf) {
#pragma unroll
        for (int i = 0; i < 3; ++i) {
            int idx = i * 256 + tid;            // 0..767; plane split at 384 (64-aligned)
            int p   = (idx >= 384) ? 1 : 0;
            int li  = idx - p * 384;            // 0..383
            const unsigned short* base = p ? wtlo : wthi;
            const unsigned short* src  = base + (size_t)(col0 + (li >> 3)) * 1024
                                         + t * 64 + (li & 7) * 8;
            gload16(src, (char*)&Bs[buf][p][0] + (size_t)li * 16);
        }
    };
    auto writeA = [&](int buf) {
#pragma unroll
        for (int i = 0; i < 4; ++i) {
            int f4 = i * 256 + tid;
            int r = f4 >> 4, c4 = f4 & 15;
            float4 v = xn[i];
            unsigned short h0 = f2bf(v.x), h1 = f2bf(v.y),
                           h2 = f2bf(v.z), h3 = f2bf(v.w);
            unsigned short l0 = f2bf(v.x - bf2f(h0)), l1 = f2bf(v.y - bf2f(h1)),
                           l2 = f2bf(v.z - bf2f(h2)), l3 = f2bf(v.w - bf2f(h3));
            uint2 uh = { (unsigned)h0 | ((unsigned)h1 << 16),
                         (unsigned)h2 | ((unsigned)h3 << 16) };
            uint2 ul = { (unsigned)l0 | ((unsigned)l1 << 16),
                         (unsigned)l2 | ((unsigned)l3 << 16) };
            int byte = r * 128 + (((c4 >> 1) ^ (r & 7)) << 4) + ((c4 & 1) << 3);
            *reinterpret_cast<uint2*>((char*)&As[buf][0][0] + byte) = uh;
            *reinterpret_cast<uint2*>((char*)&As[buf][1][0] + byte) = ul;
        }
    };

    f32x4 acc[3];
    acc[0] = acc[1] = acc[2] = (f32x4){0.f, 0.f, 0.f, 0.f};

    loadX(0);
    stageB(0, 0);
    writeA(0);

    const int arow = w * 16 + i16;
    for (int t = 0; t < 16; ++t) {
        const int b = t & 1;
        __syncthreads();                 // buf b staged (vmcnt+lgkm drained)
        if (t < 15) {
            loadX(t + 1);                // in flight during MFMA
            stageB(t + 1, b ^ 1);        // async into other buffer
        }
        bf16x8 ah[2], al[2];
#pragma unroll
        for (int kc = 0; kc < 2; ++kc) {
            int off = arow * 128 + ((((kc << 2) | g16) ^ (arow & 7)) << 4);
            ah[kc] = *reinterpret_cast<const bf16x8*>((char*)&As[b][0][0] + off);
            al[kc] = *reinterpret_cast<const bf16x8*>((char*)&As[b][1][0] + off);
        }
#pragma unroll
        for (int ct = 0; ct < 3; ++ct) {
            const int colL = ct * 16 + i16;
#pragma unroll
            for (int kc = 0; kc < 2; ++kc) {
                int off = colL * 128 + ((((kc << 2) | g16) ^ (colL & 7)) << 4);
                bf16x8 bh = *reinterpret_cast<const bf16x8*>((char*)&Bs[b][0][0] + off);
                bf16x8 bl = *reinterpret_cast<const bf16x8*>((char*)&Bs[b][1][0] + off);
                acc[ct] = __builtin_amdgcn_mfma_f32_16x16x32_bf16(ah[kc], bh, acc[ct], 0, 0, 0);
                acc[ct] = __builtin_amdgcn_mfma_f32_16x16x32_bf16(ah[kc], bl, acc[ct], 0, 0, 0);
                acc[ct] = __builtin_amdgcn_mfma_f32_16x16x32_bf16(al[kc], bh, acc[ct], 0, 0, 0);
            }
        }
        if (t < 15) writeA(b ^ 1);
    }

    // epilogue: attn-ready planes (round-6 verified layouts)
    const float QSCALE = 0.180336880f;   // log2(e)/8 folded into q
#pragma unroll
    for (int ct = 0; ct < 3; ++ct) {
        int cglob = col0 + ct * 16 + i16;
        int g = cglob >> 6, c64 = cglob & 63;
#pragma unroll
        for (int rr = 0; rr < 4; ++rr) {
            int row = row0 + w * 16 + 4 * g16 + rr;
            float f = acc[ct][rr];
            if (g == 0) {
                f *= QSCALE;
                unsigned short h = f2bf(f);
                qhi[(size_t)row * 64 + c64] = h;
                qlo[(size_t)row * 64 + c64] = f2bf(f - bf2f(h));
            } else if (g == 1) {
                int ci = c64 ^ ((row & 7) << 3);
                unsigned short h = f2bf(f);
                khi[(size_t)row * 64 + ci] = h;
                klo[(size_t)row * 64 + ci] = f2bf(f - bf2f(h));
            } else {
                int cg  = row >> 3;
                int cgs = (cg & ~7) | ((cg & 7) ^ (c64 & 7));
                vthi[(size_t)c64 * 8192 + cgs * 8 + (row & 7)] = f2bf(f);
            }
        }
    }
}

// ---------------------------------------------------------------------------
// Flash attention. QK^T split-bf16 3-term; PV 1-term bf16. Scores arrive in
// log2 domain (scale baked into q) -> exp2f. Row-sums via MFMA ones-trick:
// l lives in accumulator o5 (o5 = o5*corr + P @ ones). Staging via
// global_load_lds. 4 waves x 16 q-rows, BK=64, split-K + combine.
// ---------------------------------------------------------------------------
constexpr int BQ = 64;
constexpr int BK = 64;

__global__ __launch_bounds__(256) void attn_kernel(
    const unsigned short* __restrict__ qhi, const unsigned short* __restrict__ qlo,
    const unsigned short* __restrict__ khi, const unsigned short* __restrict__ klo,
    const unsigned short* __restrict__ vthi,
    float* __restrict__ po, float* __restrict__ pm, float* __restrict__ pl,
    int keys_per_split)
{
    __shared__ unsigned short stage[12288];        // 24KB: khi|klo|vthi 8KB each
    __shared__ unsigned short pThi[4][16][72];

    const int tid  = threadIdx.x;
    const int lane = tid & 63;
    const int w    = tid >> 6;
    const int g16  = lane >> 4;
    const int i16  = lane & 15;
    const int qrow0 = blockIdx.x * BQ;
    const int split = blockIdx.y;
    const int key0  = split * keys_per_split;
    const int nt    = keys_per_split / BK;

    bf16x8 qh[2], ql[2];
    {
        const size_t qr = (size_t)(qrow0 + w * 16 + i16) * 64;
#pragma unroll
        for (int c = 0; c < 2; ++c) {
            qh[c] = *reinterpret_cast<const bf16x8*>(qhi + qr + c * 32 + g16 * 8);
            ql[c] = *reinterpret_cast<const bf16x8*>(qlo + qr + c * 32 + g16 * 8);
        }
    }
    bf16x8 ones;
#pragma unroll
    for (int e = 0; e < 8; ++e) ones[e] = (short)0x3F80;   // bf16 1.0

    float m_r[4];
    f32x4 o_acc[4], o5;
#pragma unroll
    for (int r = 0; r < 4; ++r) m_r[r] = -INFINITY;
#pragma unroll
    for (int db = 0; db < 4; ++db) o_acc[db] = {0.f, 0.f, 0.f, 0.f};
    o5 = {0.f, 0.f, 0.f, 0.f};

    for (int t = 0; t < nt; ++t) {
        const int key0t = key0 + t * BK;
        __syncthreads();
        // stage 24KB via global_load_lds (layout swizzles pre-baked by proj)
#pragma unroll
        for (int u = 0; u < 6; ++u) {
            int row = ((u & 1) << 5) + (tid >> 3);
            int ch  = tid & 7;
            const unsigned short* src;
            if (u < 2)      src = khi  + (size_t)(key0t + row) * 64 + ch * 8;
            else if (u < 4) src = klo  + (size_t)(key0t + row) * 64 + ch * 8;
            else            src = vthi + (size_t)row * 8192 + key0t + ch * 8;
            gload16(src, (char*)stage + u * 4096 + tid * 16);
        }
        __syncthreads();

        // ---- QK^T: 4 col-tiles x 2 k-chunks x 3 split-terms ----
        f32x4 sacc[4];
#pragma unroll
        for (int j = 0; j < 4; ++j) {
            f32x4 a = {0.f, 0.f, 0.f, 0.f};
#pragma unroll
            for (int c = 0; c < 2; ++c) {
                const int kr    = 16 * j + i16;
                const int byteO = ((kr * 128 + c * 64 + g16 * 16) ^ ((kr & 7) << 4));
                bf16x8 kh = *reinterpret_cast<const bf16x8*>(
                    reinterpret_cast<const char*>(stage) + byteO);
                bf16x8 kl = *reinterpret_cast<const bf16x8*>(
                    reinterpret_cast<const char*>(stage) + byteO + 8192);
                a = __builtin_amdgcn_mfma_f32_16x16x32_bf16(qh[c], kh, a, 0, 0, 0);
                a = __builtin_amdgcn_mfma_f32_16x16x32_bf16(qh[c], kl, a, 0, 0, 0);
                a = __builtin_amdgcn_mfma_f32_16x16x32_bf16(ql[c], kh, a, 0, 0, 0);
            }
            sacc[j] = a;
        }

        // ---- online softmax (log2 domain); lane's rows: 4*g16 + r ----
        float p4[4][4];
        float corrv[4];
#pragma unroll
        for (int r = 0; r < 4; ++r) {
            float a = fmaxf(fmaxf(sacc[0][r], sacc[1][r]),
                            fmaxf(sacc[2][r], sacc[3][r]));
#pragma unroll
            for (int msk = 1; msk < 16; msk <<= 1)
                a = fmaxf(a, __shfl_xor(a, msk, 16));
            float mn = fmaxf(m_r[r], a);
            corrv[r] = exp2f(m_r[r] - mn);
            m_r[r] = mn;
#pragma unroll
            for (int j = 0; j < 4; ++j)
                p4[j][r] = exp2f(sacc[j][r] - mn);
        }
        {
            f32x4 cv = {corrv[0], corrv[1], corrv[2], corrv[3]};
#pragma unroll
            for (int db = 0; db < 4; ++db) o_acc[db] *= cv;
            o5 *= cv;
        }

        // ---- P (bf16) into per-wave LDS plane (same-wave consumer) ----
#pragma unroll
        for (int j = 0; j < 4; ++j)
#pragma unroll
            for (int r = 0; r < 4; ++r)
                pThi[w][4 * g16 + r][16 * j + i16] = f2bf(p4[j][r]);

        // ---- PV (1-term) + row-sum via ones-MFMA ----
        bf16x8 ph[2];
#pragma unroll
        for (int c = 0; c < 2; ++c)
            ph[c] = *reinterpret_cast<const bf16x8*>(&pThi[w][i16][32 * c + 8 * g16]);
        o5 = __builtin_amdgcn_mfma_f32_16x16x32_bf16(ph[0], ones, o5, 0, 0, 0);
        o5 = __builtin_amdgcn_mfma_f32_16x16x32_bf16(ph[1], ones, o5, 0, 0, 0);
#pragma unroll
        for (int db = 0; db < 4; ++db) {
            f32x4 a = o_acc[db];
#pragma unroll
            for (int c = 0; c < 2; ++c) {
                const int vr    = 16 * db + i16;
                const int byteO = ((vr * 128 + c * 64 + g16 * 16) ^ ((vr & 7) << 4)) + 16384;
                bf16x8 vh = *reinterpret_cast<const bf16x8*>(
                    reinterpret_cast<const char*>(stage) + byteO);
                a = __builtin_amdgcn_mfma_f32_16x16x32_bf16(ph[c], vh, a, 0, 0, 0);
            }
            o_acc[db] = a;
        }
    }

    const size_t prow = (size_t)split * N + qrow0 + w * 16;
#pragma unroll
    for (int db = 0; db < 4; ++db)
#pragma unroll
        for (int r = 0; r < 4; ++r)
            po[(prow + 4 * g16 + r) * 64 + 16 * db + i16] = o_acc[db][r];
    if (i16 == 0) {
#pragma unroll
        for (int r = 0; r < 4; ++r) {
            pm[prow + 4 * g16 + r] = m_r[r];      // log2-domain max
            pl[prow + 4 * g16 + r] = o5[r];       // row-sum from ones-MFMA
        }
    }
}

// ---------------------------------------------------------------------------
// Combine split-K partials (log2-domain maxima -> exp2f weights).
// ---------------------------------------------------------------------------
__global__ __launch_bounds__(256) void combine_kernel(
    const float* __restrict__ po,
    const float* __restrict__ pm,
    const float* __restrict__ pl,
    float* __restrict__ out, int ns)
{
    const int tid = threadIdx.x;
    const int row = blockIdx.x * 16 + (tid >> 4);
    const int c4  = tid & 15;

    float M = -INFINITY;
    for (int s = 0; s < ns; ++s)
        M = fmaxf(M, pm[(size_t)s * N + row]);
    float L = 0.f;
    float4 acc = {0.f, 0.f, 0.f, 0.f};
    for (int s = 0; s < ns; ++s) {
        float ws = exp2f(pm[(size_t)s * N + row] - M);
        L += ws * pl[(size_t)s * N + row];
        float4 ov = *reinterpret_cast<const float4*>(
            po + ((size_t)s * N + row) * 64 + c4 * 4);
        acc.x += ws * ov.x; acc.y += ws * ov.y;
        acc.z += ws * ov.z; acc.w += ws * ov.w;
    }
    float inv = 1.f / L;
    float4 res = {acc.x * inv, acc.y * inv, acc.z * inv, acc.w * inv};
    *reinterpret_cast<float4*>(out + (size_t)row * 64 + c4 * 4) = res;
}

// ---------------------------------------------------------------------------
extern "C" void kernel_launch(void* const* d_in, const int* in_sizes, int n_in,
                              void* d_out, int out_size, void* d_ws, size_t ws_size,
                              hipStream_t stream)
{
    const float* x  = (const float*)d_in[0];
    const float* wq = (const float*)d_in[1];
    const float* wk = (const float*)d_in[2];
    const float* wv = (const float*)d_in[3];
    float* out = (float*)d_out;

    const size_t PLANE = (size_t)N * 64;               // ushorts per plane
    unsigned short* qhi  = (unsigned short*)d_ws;
    unsigned short* qlo  = qhi + PLANE;
    unsigned short* khi  = qlo + PLANE;
    unsigned short* klo  = khi + PLANE;
    unsigned short* vthi = klo + PLANE;
    const size_t plane_bytes = 5 * PLANE * 2;          // 5 MB
    const size_t wt_elems = (size_t)192 * 1024;
    const size_t wt_bytes = 2 * wt_elems * 2;          // 786 KB

    int ns = 8;
    while (ns > 1 &&
           plane_bytes + wt_bytes +
           (size_t)ns * ((size_t)N * 64 * 4 + (size_t)N * 8) > ws_size)
        ns >>= 1;

    float* po = (float*)((char*)d_ws + plane_bytes);
    float* pm = po + (size_t)ns * N * 64;
    float* pl = pm + (size_t)ns * N;
    unsigned short* wthi = (unsigned short*)(pl + (size_t)ns * N);
    unsigned short* wtlo = wthi + wt_elems;

    prep_w_kernel<<<768, 256, 0, stream>>>(wq, wk, wv, wthi, wtlo);

    dim3 pgrid(N / 64, 4);
    proj_kernel<<<pgrid, 256, 0, stream>>>(x, wthi, wtlo,
                                           qhi, qlo, khi, klo, vthi);

    dim3 agrid(N / BQ, ns);
    attn_kernel<<<agrid, 256, 0, stream>>>(qhi, qlo, khi, klo, vthi,
                                           po, pm, pl, N / ns);

    combine_kernel<<<N / 16, 256, 0, stream>>>(po, pm, pl, out, ns);
}